// Round 3
// baseline (322.081 us; speedup 1.0000x reference)
//
#include <hip/hip_runtime.h>
#include <hip/hip_bf16.h>

#define N_NODES 50000
#define N_EDGES 800000
#define MP 50048  // N_NODES padded to multiple of 64

typedef unsigned short ushort_t;
typedef unsigned int uint_t;
typedef __attribute__((ext_vector_type(8))) __bf16 bf16x8;
typedef __attribute__((ext_vector_type(4))) float f32x4;

__device__ __forceinline__ float bf2f(uint_t u) {
    union { uint_t i; float f; } v; v.i = u << 16; return v.f;
}
__device__ __forceinline__ ushort_t f2bf(float f) {
    union { float f; uint_t i; } v; v.f = f;
    uint_t u = v.i;
    return (ushort_t)((u + 0x7FFFu + ((u >> 16) & 1u)) >> 16);
}
__device__ __forceinline__ void acc4(float* a, uint2 d) {
    a[0] += bf2f(d.x & 0xffff); a[1] += bf2f(d.x >> 16);
    a[2] += bf2f(d.y & 0xffff); a[3] += bf2f(d.y >> 16);
}

// ---------------- CSR build ----------------
__global__ void deg_k(const int* __restrict__ dst, int* __restrict__ deg, int E) {
    int e = blockIdx.x * 256 + threadIdx.x;
    if (e < E) atomicAdd(&deg[dst[e]], 1);
}

__global__ void scan1_k(const int* __restrict__ deg, int* __restrict__ offs,
                        int* __restrict__ bsum, int n) {
    __shared__ int s[256];
    int i = blockIdx.x * 256 + threadIdx.x;
    int v = (i < n) ? deg[i] : 0;
    s[threadIdx.x] = v;
    __syncthreads();
    #pragma unroll
    for (int d = 1; d < 256; d <<= 1) {
        int t = (threadIdx.x >= d) ? s[threadIdx.x - d] : 0;
        __syncthreads();
        s[threadIdx.x] += t;
        __syncthreads();
    }
    if (i < n) offs[i] = s[threadIdx.x] - v;   // exclusive
    if (threadIdx.x == 255) bsum[blockIdx.x] = s[255];
}

__global__ void scan2_k(int* __restrict__ bsum, int nb) {  // single block
    __shared__ int s[256];
    int v = (threadIdx.x < nb) ? bsum[threadIdx.x] : 0;
    s[threadIdx.x] = v;
    __syncthreads();
    #pragma unroll
    for (int d = 1; d < 256; d <<= 1) {
        int t = (threadIdx.x >= d) ? s[threadIdx.x - d] : 0;
        __syncthreads();
        s[threadIdx.x] += t;
        __syncthreads();
    }
    if (threadIdx.x < nb) bsum[threadIdx.x] = s[threadIdx.x] - v;  // exclusive
}

__global__ void scan3_k(int* __restrict__ offs, const int* __restrict__ bsum, int n, int E) {
    int i = blockIdx.x * 256 + threadIdx.x;
    if (i < n) offs[i] += bsum[blockIdx.x];
    if (i == 0) offs[n] = E;
}

__global__ void scat_k(const int* __restrict__ src, const int* __restrict__ dst,
                       int* __restrict__ cur, int* __restrict__ csrc, int E) {
    int e = blockIdx.x * 256 + threadIdx.x;
    if (e < E) {
        int p = atomicAdd(&cur[dst[e]], 1);
        csrc[p] = src[e];
    }
}

// ---------------- f32 -> bf16 convert ----------------
__global__ void cvt_k(const float* __restrict__ x, ushort_t* __restrict__ o, long long n) {
    long long i = ((long long)blockIdx.x * 256 + threadIdx.x) * 4;
    if (i >= n) return;
    float4 v = *reinterpret_cast<const float4*>(x + i);
    uint2 w;
    w.x = (uint_t)f2bf(v.x) | ((uint_t)f2bf(v.y) << 16);
    w.y = (uint_t)f2bf(v.z) | ((uint_t)f2bf(v.w) << 16);
    *reinterpret_cast<uint2*>(o + i) = w;
}

// ---------------- weight-pair packing into MFMA B-fragment order ----------------
// packs [Wl | Wr] (each [K,F]) as one [K, 2F] matrix in frag order.
// frag (kt, ct): value(lane, j) = W[kt*32 + (lane>>4)*8 + j][ct*16 + (lane&15)]
__global__ void pack2_k(const float* __restrict__ Wl, const float* __restrict__ Wr,
                        ushort_t* __restrict__ P, int K, int F) {
    int NOUT = 2 * F;
    int tid = blockIdx.x * 256 + threadIdx.x;
    int total = (K / 32) * (NOUT / 16) * 64;
    if (tid >= total) return;
    int lane = tid & 63;
    int frag = tid >> 6;
    int nct = NOUT / 16;
    int ct = frag % nct;
    int kt = frag / nct;
    int col = ct * 16 + (lane & 15);
    const float* W = (col < F) ? Wl : Wr;
    int c = (col < F) ? col : col - F;
    int k0 = kt * 32 + (lane >> 4) * 8;
    uint_t w[4];
    #pragma unroll
    for (int p = 0; p < 4; ++p) {
        ushort_t lo = f2bf(W[(long long)(k0 + 2 * p) * F + c]);
        ushort_t hi = f2bf(W[(long long)(k0 + 2 * p + 1) * F + c]);
        w[p] = (uint_t)lo | ((uint_t)hi << 16);
    }
    *(reinterpret_cast<uint4*>(P) + tid) = make_uint4(w[0], w[1], w[2], w[3]);
}

// ---------------- GEMM: C[MP,NOUT] = A[MP,K] @ Bp (frag-packed) ----------------
template <int K, int NOUT>
__global__ __launch_bounds__(256) void gemm_k(
    const ushort_t* __restrict__ A, const ushort_t* __restrict__ Bp,
    ushort_t* __restrict__ C) {
    constexpr int KT = K / 32;
    constexpr int CTW = NOUT / 64;
    int wave = threadIdx.x >> 6;
    int lane = threadIdx.x & 63;
    int rowBase = blockIdx.x * 64;
    int arowoff = lane & 15;
    int kgrp = (lane >> 4) * 8;
    int ct0 = wave * CTW;

    f32x4 acc[4][CTW];
    #pragma unroll
    for (int r = 0; r < 4; ++r)
        #pragma unroll
        for (int c = 0; c < CTW; ++c) acc[r][c] = (f32x4){0.f, 0.f, 0.f, 0.f};

    const ushort_t* Ab = A + (long long)rowBase * K + kgrp;
    #pragma unroll
    for (int kt = 0; kt < KT; ++kt) {
        bf16x8 a[4];
        #pragma unroll
        for (int r = 0; r < 4; ++r)
            a[r] = *reinterpret_cast<const bf16x8*>(
                Ab + (long long)(r * 16 + arowoff) * K + kt * 32);
        #pragma unroll
        for (int ct = 0; ct < CTW; ++ct) {
            bf16x8 b = *reinterpret_cast<const bf16x8*>(
                Bp + ((long long)(kt * (NOUT / 16) + ct0 + ct) * 64 + lane) * 8);
            #pragma unroll
            for (int r = 0; r < 4; ++r)
                acc[r][ct] = __builtin_amdgcn_mfma_f32_16x16x32_bf16(a[r], b, acc[r][ct], 0, 0, 0);
        }
    }

    int colb = lane & 15;
    int r0 = (lane >> 4) * 4;
    #pragma unroll
    for (int r = 0; r < 4; ++r) {
        #pragma unroll
        for (int ct = 0; ct < CTW; ++ct) {
            int col = (ct0 + ct) * 16 + colb;
            #pragma unroll
            for (int j = 0; j < 4; ++j) {
                int row = rowBase + r * 16 + r0 + j;
                C[(long long)row * NOUT + col] = f2bf(acc[r][ct][j]);
            }
        }
    }
}

// ---------------- fused aggregate + epilogue, 2 nodes/wave, deep MLP ----------------
// C = [P | R] rows of width 2F. out = act(segmean_gather(P) + R + bias).
// LPG = F/4 lanes cover a row at 8B/lane; G = 64/LPG edges concurrent per node;
// 4 edges per node per iteration, 2 nodes => 8 gathers in flight.
template <int F, bool RELU, bool FINAL>
__global__ __launch_bounds__(256, 6) void agg_k(
    const ushort_t* __restrict__ C, const int* __restrict__ offs,
    const int* __restrict__ csrc, const float* __restrict__ bias,
    ushort_t* __restrict__ H, float* __restrict__ hout,
    float* __restrict__ lout, int n) {
    constexpr int LPG = F / 4;     // 64, 32, 16
    constexpr int G = 64 / LPG;    // 1, 2, 4
    constexpr int U = 4 / G;       // 4, 2, 1
    constexpr int S = 2 * F;       // row stride (elems)
    int wid = (blockIdx.x * 256 + threadIdx.x) >> 6;
    int lane = threadIdx.x & 63;
    int g = (G == 1) ? 0 : (lane / LPG);
    int sub = lane & (LPG - 1);
    int colbase = sub * 4;
    int n0 = 2 * wid, n1 = 2 * wid + 1;
    if (n0 >= n) return;
    bool has1 = (n1 < n);
    int b0 = offs[n0], end0 = offs[n0 + 1];
    int b1 = has1 ? offs[n1] : 0, end1 = has1 ? offs[n1 + 1] : 0;

    float a0[4] = {0.f, 0.f, 0.f, 0.f};
    float a1[4] = {0.f, 0.f, 0.f, 0.f};
    int e0 = b0, e1 = b1;

    // steady state: 8 independent gathers in flight (4 edges each node)
    while (e0 + 4 <= end0 && e1 + 4 <= end1) {
        uint2 d0[U], d1[U];
        #pragma unroll
        for (int u = 0; u < U; ++u) {
            int s = csrc[e0 + g + u * G];
            d0[u] = *reinterpret_cast<const uint2*>(C + (size_t)s * S + colbase);
        }
        #pragma unroll
        for (int u = 0; u < U; ++u) {
            int s = csrc[e1 + g + u * G];
            d1[u] = *reinterpret_cast<const uint2*>(C + (size_t)s * S + colbase);
        }
        #pragma unroll
        for (int u = 0; u < U; ++u) { acc4(a0, d0[u]); acc4(a1, d1[u]); }
        e0 += 4; e1 += 4;
    }
    // drain node0: 4-edge batches, then predicated singles
    while (e0 + 4 <= end0) {
        uint2 d[U];
        #pragma unroll
        for (int u = 0; u < U; ++u) {
            int s = csrc[e0 + g + u * G];
            d[u] = *reinterpret_cast<const uint2*>(C + (size_t)s * S + colbase);
        }
        #pragma unroll
        for (int u = 0; u < U; ++u) acc4(a0, d[u]);
        e0 += 4;
    }
    for (int e = e0 + g; e < end0; e += G) {
        int s = csrc[e];
        uint2 d = *reinterpret_cast<const uint2*>(C + (size_t)s * S + colbase);
        acc4(a0, d);
    }
    // drain node1
    while (e1 + 4 <= end1) {
        uint2 d[U];
        #pragma unroll
        for (int u = 0; u < U; ++u) {
            int s = csrc[e1 + g + u * G];
            d[u] = *reinterpret_cast<const uint2*>(C + (size_t)s * S + colbase);
        }
        #pragma unroll
        for (int u = 0; u < U; ++u) acc4(a1, d[u]);
        e1 += 4;
    }
    for (int e = e1 + g; e < end1; e += G) {
        int s = csrc[e];
        uint2 d = *reinterpret_cast<const uint2*>(C + (size_t)s * S + colbase);
        acc4(a1, d);
    }

    // combine partial sums across the G groups
    if (G > 1) {
        #pragma unroll
        for (int off = LPG; off < 64; off <<= 1) {
            #pragma unroll
            for (int i = 0; i < 4; ++i) {
                a0[i] += __shfl_xor(a0[i], off);
                a1[i] += __shfl_xor(a1[i], off);
            }
        }
    }

    float inv0 = 1.f / fmaxf((float)(end0 - b0), 1.f);
    float inv1 = 1.f / fmaxf((float)(end1 - b1), 1.f);

    if constexpr (!FINAL) {
        if (lane < LPG) {
            #pragma unroll
            for (int j = 0; j < 2; ++j) {
                int node = j ? n1 : n0;
                if (j && !has1) break;
                float* a = j ? a1 : a0;
                float inv = j ? inv1 : inv0;
                uint2 rr = *reinterpret_cast<const uint2*>(C + (size_t)node * S + F + colbase);
                float4 bv = *reinterpret_cast<const float4*>(bias + colbase);
                float v0 = a[0] * inv + bf2f(rr.x & 0xffff) + bv.x;
                float v1 = a[1] * inv + bf2f(rr.x >> 16) + bv.y;
                float v2 = a[2] * inv + bf2f(rr.y & 0xffff) + bv.z;
                float v3 = a[3] * inv + bf2f(rr.y >> 16) + bv.w;
                if (RELU) {
                    v0 = fmaxf(v0, 0.f); v1 = fmaxf(v1, 0.f);
                    v2 = fmaxf(v2, 0.f); v3 = fmaxf(v3, 0.f);
                }
                uint2 w;
                w.x = (uint_t)f2bf(v0) | ((uint_t)f2bf(v1) << 16);
                w.y = (uint_t)f2bf(v2) | ((uint_t)f2bf(v3) << 16);
                *reinterpret_cast<uint2*>(H + (size_t)node * F + colbase) = w;
            }
        }
    } else {
        #pragma unroll
        for (int j = 0; j < 2; ++j) {
            int node = j ? n1 : n0;
            if (j && !has1) break;
            float* a = j ? a1 : a0;
            float inv = j ? inv1 : inv0;
            uint2 rr = *reinterpret_cast<const uint2*>(C + (size_t)node * S + F + colbase);
            float4 bv = *reinterpret_cast<const float4*>(bias + colbase);
            float v0 = a[0] * inv + bf2f(rr.x & 0xffff) + bv.x;
            float v1 = a[1] * inv + bf2f(rr.x >> 16) + bv.y;
            float v2 = a[2] * inv + bf2f(rr.y & 0xffff) + bv.z;
            float v3 = a[3] * inv + bf2f(rr.y >> 16) + bv.w;
            float m = fmaxf(fmaxf(v0, v1), fmaxf(v2, v3));
            #pragma unroll
            for (int off = 1; off < LPG; off <<= 1) m = fmaxf(m, __shfl_xor(m, off));
            float s = expf(v0 - m) + expf(v1 - m) + expf(v2 - m) + expf(v3 - m);
            #pragma unroll
            for (int off = 1; off < LPG; off <<= 1) s += __shfl_xor(s, off);
            float ls = logf(s);
            if (lane < LPG) {
                *reinterpret_cast<float4*>(hout + (size_t)node * 64 + colbase) =
                    make_float4(v0, v1, v2, v3);
                *reinterpret_cast<float4*>(lout + (size_t)node * 64 + colbase) =
                    make_float4(v0 - m - ls, v1 - m - ls, v2 - m - ls, v3 - m - ls);
            }
        }
    }
}

extern "C" void kernel_launch(void* const* d_in, const int* in_sizes, int n_in,
                              void* d_out, int out_size, void* d_ws, size_t ws_size,
                              hipStream_t stream) {
    const float* x   = (const float*)d_in[0];
    const int*   ei  = (const int*)d_in[1];
    const float* W1l = (const float*)d_in[2];
    const float* b1  = (const float*)d_in[3];
    const float* W1r = (const float*)d_in[4];
    const float* W2l = (const float*)d_in[5];
    const float* b2  = (const float*)d_in[6];
    const float* W2r = (const float*)d_in[7];
    const float* W3l = (const float*)d_in[8];
    const float* b3  = (const float*)d_in[9];
    const float* W3r = (const float*)d_in[10];
    const int* esrc = ei;
    const int* edst = ei + N_EDGES;

    char* ws = (char*)d_ws;
    size_t off = 0;
    auto alloc = [&](size_t b) { void* p = ws + off; off = (off + b + 255) & ~(size_t)255; return p; };
    ushort_t* bufA = (ushort_t*)alloc((size_t)MP * 256 * 2);
    ushort_t* bufB = (ushort_t*)alloc((size_t)MP * 512 * 2);
    ushort_t* bufC = (ushort_t*)alloc((size_t)MP * 256 * 2);
    int* offs = (int*)alloc((N_NODES + 1) * 4);
    int* cur  = (int*)alloc(N_NODES * 4);
    int* csrc = (int*)alloc(N_EDGES * 4);
    int* bsum = (int*)alloc(256 * 4);
    ushort_t* pB1 = (ushort_t*)alloc(256 * 512 * 2);
    ushort_t* pB2 = (ushort_t*)alloc(256 * 256 * 2);
    ushort_t* pB3 = (ushort_t*)alloc(128 * 128 * 2);

    ushort_t* Xbf = bufA;
    ushort_t* C1  = bufB;
    ushort_t* H1  = bufC;
    ushort_t* C2  = bufA;
    ushort_t* H2  = bufB;
    ushort_t* C3  = bufC;

    int nScanBlocks = (N_NODES + 255) / 256;  // 196

    // CSR build (reused by all 3 layers)
    hipMemsetAsync(cur, 0, N_NODES * 4, stream);
    deg_k<<<(N_EDGES + 255) / 256, 256, 0, stream>>>(edst, cur, N_EDGES);
    scan1_k<<<nScanBlocks, 256, 0, stream>>>(cur, offs, bsum, N_NODES);
    scan2_k<<<1, 256, 0, stream>>>(bsum, nScanBlocks);
    scan3_k<<<nScanBlocks, 256, 0, stream>>>(offs, bsum, N_NODES, N_EDGES);
    hipMemcpyAsync(cur, offs, N_NODES * 4, hipMemcpyDeviceToDevice, stream);
    scat_k<<<(N_EDGES + 255) / 256, 256, 0, stream>>>(esrc, edst, cur, csrc, N_EDGES);

    // x -> bf16
    cvt_k<<<(int)(((long long)N_NODES * 256 / 4 + 255) / 256), 256, 0, stream>>>(
        x, Xbf, (long long)N_NODES * 256);

    // pack weight pairs [Wl|Wr]
    pack2_k<<<(16384 + 255) / 256, 256, 0, stream>>>(W1l, W1r, pB1, 256, 256);
    pack2_k<<<(8192 + 255) / 256, 256, 0, stream>>>(W2l, W2r, pB2, 256, 128);
    pack2_k<<<(2048 + 255) / 256, 256, 0, stream>>>(W3l, W3r, pB3, 128, 64);

    int gemmGrid = MP / 64;                         // 782
    int aggGrid = ((N_NODES + 1) / 2 + 3) / 4;      // 25000 waves, 4/block -> 6250
    float* hout = (float*)d_out;
    float* lout = hout + (long long)N_NODES * 64;

    // layer 1
    gemm_k<256, 512><<<gemmGrid, 256, 0, stream>>>(Xbf, pB1, C1);
    agg_k<256, true, false><<<aggGrid, 256, 0, stream>>>(
        C1, offs, csrc, b1, H1, nullptr, nullptr, N_NODES);
    // layer 2
    gemm_k<256, 256><<<gemmGrid, 256, 0, stream>>>(H1, pB2, C2);
    agg_k<128, true, false><<<aggGrid, 256, 0, stream>>>(
        C2, offs, csrc, b2, H2, nullptr, nullptr, N_NODES);
    // layer 3 (+ fused log_softmax)
    gemm_k<128, 128><<<gemmGrid, 256, 0, stream>>>(H2, pB3, C3);
    agg_k<64, false, true><<<aggGrid, 256, 0, stream>>>(
        C3, offs, csrc, b3, nullptr, hout, lout, N_NODES);
}